// Round 17
// baseline (176.205 us; speedup 1.0000x reference)
//
#include <hip/hip_runtime.h>
#include <hip/hip_bf16.h>

#define LDIM 8192
#define HDIM 16
#define DDIM 64
#define NHEADPAIR 64          // N*H
#define ROWSTRIDE 1024        // H*D floats between consecutive l for fixed h
#define KVSZ 4160             // 64*64 KV + 64 ksum
#define EPSF 1e-6f
#define CHUNKS 128            // l-chunks per (n,h)
#define RPB 64                // rows per block = LDIM/CHUNKS
#define LROW 36               // padded LDS row in uints (32 l-pair slots + 4 pad)

typedef float f32x4 __attribute__((ext_vector_type(4)));
typedef short s16x8 __attribute__((ext_vector_type(8)));   // 8 bf16 (4 VGPRs)

__device__ __forceinline__ float featmap(float x) {
    // elu(x)+1 : x>0 -> x+1 ; x<=0 -> exp(x)
    return x > 0.0f ? x + 1.0f : __expf(x);
}

__device__ __forceinline__ unsigned int pack_bf16x2(float a, float b) {
    union { __hip_bfloat162 h; unsigned int u; } x;
    x.h = __float22bfloat162_rn(make_float2(a, b));   // elem0 -> low 16 bits
    return x.u;
}

__device__ __forceinline__ unsigned short bf16_of(float a) {
    union { __hip_bfloat16 h; unsigned short u; } cv;
    cv.h = __float2bfloat16(a);
    return cv.u;
}

// validated swizzle: XOR slot bits 2-3 with d bits 3-4 (16B-align-preserving)
__device__ __forceinline__ int swz(int d) { return ((d >> 3) & 3) << 2; }

// ---------------- Phase 1 (one-shot MFMA + cooperative dense prefetch) --------------
// R16 kernel + ONE addition: before the strided staging reads, each block issues
// DENSE prefetch loads of the full-4KB rows r with (r % 16) == h in its 64-row range
// (K for t<128, V for t>=128; 32KB/block). Across the 16 co-resident h-sibling
// blocks the union covers every 64B line of the range exactly once as a SEQUENTIAL
// stream -> DRAM page hits -> low latency. The strided staging reads then hit
// L3-warm lines or MSHR-merge with the in-flight dense fetches. Net DRAM line
// count unchanged; only the request ORDER becomes dense.
__global__ __launch_bounds__(256) void kv_oneshot_kernel(
    const float* __restrict__ Kp, const float* __restrict__ Vp,
    unsigned short* __restrict__ part)
{
    __shared__ unsigned int KT[64 * LROW];   // [d][slot ^ swz(d)]
    __shared__ unsigned int VT[64 * LROW];   // [m][slot ^ swz(m)]

    const int ch   = blockIdx.x;             // l-chunk
    const int nh   = blockIdx.y;
    const int n    = nh >> 4;
    const int h    = nh & 15;
    const int t    = threadIdx.x;
    const int wave = t >> 6;
    const int lane = t & 63;

    const bool isK   = (t < 128);
    const float* Sp  = isK ? Kp : Vp;

    // ---- cooperative dense prefetch (results discarded; lines warm L2/L3) ----
    {
        const int u  = t & 127;              // 128 threads per array
        const int q  = u >> 5;               // row-quarter 0..3
        const int fo = (u & 31) * 32;        // 128B lane-part within the 4KB row
        const size_t rbase = ((size_t)n * LDIM + (size_t)ch * RPB + h + 16 * q)
                           * ROWSTRIDE + fo;
        float s0 = 0.f;
#pragma unroll
        for (int j = 0; j < 8; ++j)
            s0 += Sp[rbase + j * 4];         // touches all 8 16B granules' lines
        asm volatile("" :: "v"(s0));         // keep the loads alive (no DCE)
    }

    // ---- strided staging (unchanged from R16): dense-instruction lane map ----
    const int  uw    = (t >> 6) & 1;         // sub-wave within the K/V half
    const int  col16 = lane & 15;            // 16B granule within a 256B row
    const int  rv    = lane >> 4;            // row-in-quad 0..3
    const size_t base = (((size_t)n * LDIM + (size_t)ch * RPB) * HDIM + h) * DDIM
                      + col16 * 4;
    unsigned int* T = isK ? KT : VT;

#pragma unroll
    for (int g = 0; g < 4; ++g) {
        const int gg = uw * 4 + g;           // 8-row group 0..7
        const int r1 = gg * 8 + rv;          // rows rv, rv+4 of the group
        const int r2 = r1 + 4;
        float4 L1 = *(const float4*)(Sp + base + (size_t)r1 * ROWSTRIDE);
        float4 L2 = *(const float4*)(Sp + base + (size_t)r2 * ROWSTRIDE);
        float a[4] = { L1.x, L1.y, L1.z, L1.w };
        float b[4] = { L2.x, L2.y, L2.z, L2.w };
        if (isK) {
#pragma unroll
            for (int j = 0; j < 4; ++j) { a[j] = featmap(a[j]); b[j] = featmap(b[j]); }
        }
        const int slot = gg * 4 + rv;        // 0..31
#pragma unroll
        for (int j = 0; j < 4; ++j) {
            const int d = col16 * 4 + j;
            T[d * LROW + (slot ^ swz(d))] = pack_bf16x2(a[j], b[j]);
        }
    }
    __syncthreads();

    // ---- compute: wave = 16-d band; 2 k-steps x (1 ksum + 4 m-tile) MFMAs ----
    const int fr = lane & 15;
    const int fk = lane >> 4;
    const int d0 = wave * 16;

    f32x4 acc[4];
    f32x4 zac = (f32x4){0.f, 0.f, 0.f, 0.f};
#pragma unroll
    for (int mb = 0; mb < 4; ++mb) acc[mb] = (f32x4){0.f, 0.f, 0.f, 0.f};
    s16x8 ones;
#pragma unroll
    for (int i = 0; i < 8; ++i) ones[i] = (short)0x3F80;   // bf16 1.0

    const int dA = d0 + fr;
#pragma unroll
    for (int kk = 0; kk < 2; ++kk) {
        const int slot = kk * 16 + fk * 4;
        s16x8 A = *(const s16x8*)&KT[dA * LROW + (slot ^ swz(dA))];
        zac = __builtin_amdgcn_mfma_f32_16x16x32_bf16(A, ones, zac, 0, 0, 0);
#pragma unroll
        for (int mb = 0; mb < 4; ++mb) {
            const int m = mb * 16 + fr;
            s16x8 B = *(const s16x8*)&VT[m * LROW + (slot ^ swz(m))];
            acc[mb] = __builtin_amdgcn_mfma_f32_16x16x32_bf16(A, B, acc[mb], 0, 0, 0);
        }
    }

    // ---- epilogue: bf16 partial. D row = d (fk*4+reg), D col = m (fr) ----
    unsigned short* p = part + ((size_t)nh * CHUNKS + ch) * KVSZ;
#pragma unroll
    for (int mb = 0; mb < 4; ++mb)
#pragma unroll
        for (int reg = 0; reg < 4; ++reg)
            p[(d0 + fk * 4 + reg) * 64 + mb * 16 + fr] = bf16_of(acc[mb][reg]);
    if (fr == 0)
#pragma unroll
        for (int reg = 0; reg < 4; ++reg)
            p[4096 + d0 + fk * 4 + reg] = bf16_of(zac[reg]);
}

// ---------------- Phase 1b: reduce bf16 partials, emit bf16 KV + ksum ---------------
__global__ __launch_bounds__(256) void kv_reduce_kernel(
    const unsigned short* __restrict__ part, unsigned short* __restrict__ kvh)
{
    const int nh = blockIdx.y;
    const int e  = blockIdx.x * 256 + threadIdx.x;
    if (e >= KVSZ) return;
    float s = 0.0f;
    for (int c = 0; c < CHUNKS; ++c) {
        union { unsigned short u; __hip_bfloat16 h; } cv;
        cv.u = part[((size_t)nh * CHUNKS + c) * KVSZ + e];
        s += __bfloat162float(cv.h);
    }
    kvh[(size_t)nh * KVSZ + e] = bf16_of(s);
}

// ---------------- Phase 2 (MFMA): out[l][m] = Z * sum_d fmQ[l][d] * KV[m][d] --------
// Unchanged (validated).
__global__ __launch_bounds__(256) void attn_mfma_kernel(
    const float* __restrict__ Qp, const unsigned short* __restrict__ kvh,
    float* __restrict__ out)
{
    __shared__ unsigned int kvU[64][36];
    __shared__ unsigned int ksU[36];
    __shared__ unsigned int qU[128][36];

    const int nh = blockIdx.y;
    const int n  = nh >> 4;
    const int h  = nh & 15;
    const int t  = threadIdx.x;

    {
        const unsigned int* kvg = (const unsigned int*)(kvh + (size_t)nh * KVSZ);
        const int r  = t >> 2;
        const int c0 = (t & 3) * 8;
        uint4 x = *(const uint4*)(kvg + r * 32 + c0);
        uint4 y = *(const uint4*)(kvg + r * 32 + c0 + 4);
        *(uint4*)&kvU[r][c0]     = x;
        *(uint4*)&kvU[r][c0 + 4] = y;
        if (t < 32) ksU[t] = kvg[2048 + t];
    }

    {
        const int qr = t >> 1;
        const float* qg = Qp + ((((size_t)n * LDIM) + (size_t)blockIdx.x * 128 + qr)
                                * HDIM + h) * DDIM + (t & 1) * 32;
        unsigned int q[16];
#pragma unroll
        for (int j = 0; j < 8; ++j) {
            float4 f = *(const float4*)(qg + j * 4);
            q[2 * j]     = pack_bf16x2(featmap(f.x), featmap(f.y));
            q[2 * j + 1] = pack_bf16x2(featmap(f.z), featmap(f.w));
        }
        uint4* dst = (uint4*)&qU[qr][(t & 1) * 16];
        dst[0] = make_uint4(q[0],  q[1],  q[2],  q[3]);
        dst[1] = make_uint4(q[4],  q[5],  q[6],  q[7]);
        dst[2] = make_uint4(q[8],  q[9],  q[10], q[11]);
        dst[3] = make_uint4(q[12], q[13], q[14], q[15]);
    }
    __syncthreads();

    const int wave = t >> 6;
    const int lane = t & 63;
    const int fr = lane & 15;
    const int fk = lane >> 4;

    s16x8 bF[4][2], kF[2];
#pragma unroll
    for (int mt = 0; mt < 4; ++mt)
#pragma unroll
        for (int kk = 0; kk < 2; ++kk)
            bF[mt][kk] = *(const s16x8*)&kvU[mt * 16 + fr][kk * 16 + fk * 4];
#pragma unroll
    for (int kk = 0; kk < 2; ++kk)
        kF[kk] = *(const s16x8*)&ksU[kk * 16 + fk * 4];

    f32x4 acc[2][4];
    f32x4 zac[2];
#pragma unroll
    for (int lt = 0; lt < 2; ++lt) {
        zac[lt] = (f32x4){0.f, 0.f, 0.f, 0.f};
#pragma unroll
        for (int mt = 0; mt < 4; ++mt) acc[lt][mt] = (f32x4){0.f, 0.f, 0.f, 0.f};
    }

#pragma unroll
    for (int kk = 0; kk < 2; ++kk) {
#pragma unroll
        for (int lt = 0; lt < 2; ++lt) {
            s16x8 A = *(const s16x8*)&qU[wave * 32 + lt * 16 + fr][kk * 16 + fk * 4];
            zac[lt] = __builtin_amdgcn_mfma_f32_16x16x32_bf16(A, kF[kk], zac[lt], 0, 0, 0);
#pragma unroll
            for (int mt = 0; mt < 4; ++mt)
                acc[lt][mt] = __builtin_amdgcn_mfma_f32_16x16x32_bf16(
                    A, bF[mt][kk], acc[lt][mt], 0, 0, 0);
        }
    }

#pragma unroll
    for (int lt = 0; lt < 2; ++lt) {
#pragma unroll
        for (int reg = 0; reg < 4; ++reg) {
            const int row = blockIdx.x * 128 + wave * 32 + lt * 16 + fk * 4 + reg;
            const float z = 1.0f / (zac[lt][reg] + EPSF);
            float* orow = out + (((size_t)n * LDIM + row) * HDIM + h) * DDIM;
#pragma unroll
            for (int mt = 0; mt < 4; ++mt)
                orow[mt * 16 + fr] = acc[lt][mt][reg] * z;
        }
    }
}

extern "C" void kernel_launch(void* const* d_in, const int* in_sizes, int n_in,
                              void* d_out, int out_size, void* d_ws, size_t ws_size,
                              hipStream_t stream) {
    const float* Q = (const float*)d_in[0];
    const float* K = (const float*)d_in[1];
    const float* V = (const float*)d_in[2];
    float* out = (float*)d_out;

    unsigned short* part = (unsigned short*)d_ws;   // 64*128*4160*2 = 68.2 MB
    unsigned short* kvh  = part + (size_t)NHEADPAIR * CHUNKS * KVSZ;

    dim3 g1(CHUNKS, NHEADPAIR);              // 8192 one-shot blocks, 8/CU resident
    kv_oneshot_kernel<<<g1, 256, 0, stream>>>(K, V, part);
    dim3 gr((KVSZ + 255) / 256, NHEADPAIR);
    kv_reduce_kernel<<<gr, 256, 0, stream>>>(part, kvh);
    dim3 g2(LDIM / 128, NHEADPAIR);
    attn_mfma_kernel<<<g2, 256, 0, stream>>>(Q, kvh, out);
}

// Round 18
// 156.289 us; speedup vs baseline: 1.1274x; 1.1274x over previous
//
#include <hip/hip_runtime.h>
#include <hip/hip_bf16.h>

#define LDIM 8192
#define HDIM 16
#define DDIM 64
#define NHEADPAIR 64          // N*H
#define ROWSTRIDE 1024        // H*D floats between consecutive l for fixed h
#define KVSZ 4160             // 64*64 KV + 64 ksum
#define EPSF 1e-6f
#define CHUNKS 128            // l-chunks per (n,h)
#define RPB 64                // rows per block = LDIM/CHUNKS
#define LROW 36               // padded LDS row in uints (32 l-pair slots + 4 pad)

typedef float f32x4 __attribute__((ext_vector_type(4)));
typedef short s16x8 __attribute__((ext_vector_type(8)));   // 8 bf16 (4 VGPRs)

__device__ __forceinline__ float featmap(float x) {
    // elu(x)+1 : x>0 -> x+1 ; x<=0 -> exp(x)
    return x > 0.0f ? x + 1.0f : __expf(x);
}

__device__ __forceinline__ unsigned int pack_bf16x2(float a, float b) {
    union { __hip_bfloat162 h; unsigned int u; } x;
    x.h = __float22bfloat162_rn(make_float2(a, b));   // elem0 -> low 16 bits
    return x.u;
}

__device__ __forceinline__ unsigned short bf16_of(float a) {
    union { __hip_bfloat16 h; unsigned short u; } cv;
    cv.h = __float2bfloat16(a);
    return cv.u;
}

// validated swizzle: XOR slot bits 2-3 with d bits 3-4 (16B-align-preserving)
__device__ __forceinline__ int swz(int d) { return ((d >> 3) & 3) << 2; }

// ---------------- Phase 1 (one-shot MFMA, page-coherent dispatch order) -------------
// R16 kernel with the grid swapped: blockIdx.x = nh (fastest). Co-dispatched blocks
// are now the 16 h-siblings (x64 nh total) at the SAME l-range, so the one-shot read
// bursts of simultaneously-starting blocks cover whole 4KB rows (all 64 lines of a
// DRAM page requested within one tight window) instead of one head's 256B slice at
// 128 different l-ranges (pages opened 16x). R17's prefetch probe proved the device
// sustains 2.5+TB/s on this data when the request stream is row-dense.
__global__ __launch_bounds__(256) void kv_oneshot_kernel(
    const float* __restrict__ Kp, const float* __restrict__ Vp,
    unsigned short* __restrict__ part)
{
    __shared__ unsigned int KT[64 * LROW];   // [d][slot ^ swz(d)]
    __shared__ unsigned int VT[64 * LROW];   // [m][slot ^ swz(m)]

    const int nh   = blockIdx.x;             // FASTEST: h-siblings co-dispatched
    const int ch   = blockIdx.y;             // l-chunk
    const int n    = nh >> 4;
    const int h    = nh & 15;
    const int t    = threadIdx.x;
    const int wave = t >> 6;
    const int lane = t & 63;

    // staging: t<128 (waves 0-1) stage K (+featmap), t>=128 stage V.
    const bool isK   = (t < 128);
    const int  uw    = (t >> 6) & 1;         // sub-wave within the K/V half
    const int  col16 = lane & 15;            // 16B granule within a 256B row
    const int  rv    = lane >> 4;            // row-in-quad 0..3
    const float* Sp  = isK ? Kp : Vp;
    const size_t base = (((size_t)n * LDIM + (size_t)ch * RPB) * HDIM + h) * DDIM
                      + col16 * 4;
    unsigned int* T = isK ? KT : VT;

#pragma unroll
    for (int g = 0; g < 4; ++g) {
        const int gg = uw * 4 + g;           // 8-row group 0..7
        const int r1 = gg * 8 + rv;          // rows rv, rv+4 of the group
        const int r2 = r1 + 4;
        float4 L1 = *(const float4*)(Sp + base + (size_t)r1 * ROWSTRIDE);
        float4 L2 = *(const float4*)(Sp + base + (size_t)r2 * ROWSTRIDE);
        float a[4] = { L1.x, L1.y, L1.z, L1.w };
        float b[4] = { L2.x, L2.y, L2.z, L2.w };
        if (isK) {
#pragma unroll
            for (int j = 0; j < 4; ++j) { a[j] = featmap(a[j]); b[j] = featmap(b[j]); }
        }
        const int slot = gg * 4 + rv;        // 0..31
#pragma unroll
        for (int j = 0; j < 4; ++j) {
            const int d = col16 * 4 + j;
            T[d * LROW + (slot ^ swz(d))] = pack_bf16x2(a[j], b[j]);
        }
    }
    __syncthreads();

    // ---- compute: wave = 16-d band; 2 k-steps x (1 ksum + 4 m-tile) MFMAs ----
    const int fr = lane & 15;
    const int fk = lane >> 4;
    const int d0 = wave * 16;

    f32x4 acc[4];
    f32x4 zac = (f32x4){0.f, 0.f, 0.f, 0.f};
#pragma unroll
    for (int mb = 0; mb < 4; ++mb) acc[mb] = (f32x4){0.f, 0.f, 0.f, 0.f};
    s16x8 ones;
#pragma unroll
    for (int i = 0; i < 8; ++i) ones[i] = (short)0x3F80;   // bf16 1.0

    const int dA = d0 + fr;
#pragma unroll
    for (int kk = 0; kk < 2; ++kk) {
        const int slot = kk * 16 + fk * 4;
        s16x8 A = *(const s16x8*)&KT[dA * LROW + (slot ^ swz(dA))];
        zac = __builtin_amdgcn_mfma_f32_16x16x32_bf16(A, ones, zac, 0, 0, 0);
#pragma unroll
        for (int mb = 0; mb < 4; ++mb) {
            const int m = mb * 16 + fr;
            s16x8 B = *(const s16x8*)&VT[m * LROW + (slot ^ swz(m))];
            acc[mb] = __builtin_amdgcn_mfma_f32_16x16x32_bf16(A, B, acc[mb], 0, 0, 0);
        }
    }

    // ---- epilogue: bf16 partial. D row = d (fk*4+reg), D col = m (fr) ----
    unsigned short* p = part + ((size_t)nh * CHUNKS + ch) * KVSZ;
#pragma unroll
    for (int mb = 0; mb < 4; ++mb)
#pragma unroll
        for (int reg = 0; reg < 4; ++reg)
            p[(d0 + fk * 4 + reg) * 64 + mb * 16 + fr] = bf16_of(acc[mb][reg]);
    if (fr == 0)
#pragma unroll
        for (int reg = 0; reg < 4; ++reg)
            p[4096 + d0 + fk * 4 + reg] = bf16_of(zac[reg]);
}

// ---------------- Phase 1b: reduce bf16 partials, emit bf16 KV + ksum ---------------
__global__ __launch_bounds__(256) void kv_reduce_kernel(
    const unsigned short* __restrict__ part, unsigned short* __restrict__ kvh)
{
    const int nh = blockIdx.y;
    const int e  = blockIdx.x * 256 + threadIdx.x;
    if (e >= KVSZ) return;
    float s = 0.0f;
    for (int c = 0; c < CHUNKS; ++c) {
        union { unsigned short u; __hip_bfloat16 h; } cv;
        cv.u = part[((size_t)nh * CHUNKS + c) * KVSZ + e];
        s += __bfloat162float(cv.h);
    }
    kvh[(size_t)nh * KVSZ + e] = bf16_of(s);
}

// ---------------- Phase 2 (MFMA): out[l][m] = Z * sum_d fmQ[l][d] * KV[m][d] --------
// Unchanged (validated).
__global__ __launch_bounds__(256) void attn_mfma_kernel(
    const float* __restrict__ Qp, const unsigned short* __restrict__ kvh,
    float* __restrict__ out)
{
    __shared__ unsigned int kvU[64][36];
    __shared__ unsigned int ksU[36];
    __shared__ unsigned int qU[128][36];

    const int nh = blockIdx.y;
    const int n  = nh >> 4;
    const int h  = nh & 15;
    const int t  = threadIdx.x;

    {
        const unsigned int* kvg = (const unsigned int*)(kvh + (size_t)nh * KVSZ);
        const int r  = t >> 2;
        const int c0 = (t & 3) * 8;
        uint4 x = *(const uint4*)(kvg + r * 32 + c0);
        uint4 y = *(const uint4*)(kvg + r * 32 + c0 + 4);
        *(uint4*)&kvU[r][c0]     = x;
        *(uint4*)&kvU[r][c0 + 4] = y;
        if (t < 32) ksU[t] = kvg[2048 + t];
    }

    {
        const int qr = t >> 1;
        const float* qg = Qp + ((((size_t)n * LDIM) + (size_t)blockIdx.x * 128 + qr)
                                * HDIM + h) * DDIM + (t & 1) * 32;
        unsigned int q[16];
#pragma unroll
        for (int j = 0; j < 8; ++j) {
            float4 f = *(const float4*)(qg + j * 4);
            q[2 * j]     = pack_bf16x2(featmap(f.x), featmap(f.y));
            q[2 * j + 1] = pack_bf16x2(featmap(f.z), featmap(f.w));
        }
        uint4* dst = (uint4*)&qU[qr][(t & 1) * 16];
        dst[0] = make_uint4(q[0],  q[1],  q[2],  q[3]);
        dst[1] = make_uint4(q[4],  q[5],  q[6],  q[7]);
        dst[2] = make_uint4(q[8],  q[9],  q[10], q[11]);
        dst[3] = make_uint4(q[12], q[13], q[14], q[15]);
    }
    __syncthreads();

    const int wave = t >> 6;
    const int lane = t & 63;
    const int fr = lane & 15;
    const int fk = lane >> 4;

    s16x8 bF[4][2], kF[2];
#pragma unroll
    for (int mt = 0; mt < 4; ++mt)
#pragma unroll
        for (int kk = 0; kk < 2; ++kk)
            bF[mt][kk] = *(const s16x8*)&kvU[mt * 16 + fr][kk * 16 + fk * 4];
#pragma unroll
    for (int kk = 0; kk < 2; ++kk)
        kF[kk] = *(const s16x8*)&ksU[kk * 16 + fk * 4];

    f32x4 acc[2][4];
    f32x4 zac[2];
#pragma unroll
    for (int lt = 0; lt < 2; ++lt) {
        zac[lt] = (f32x4){0.f, 0.f, 0.f, 0.f};
#pragma unroll
        for (int mt = 0; mt < 4; ++mt) acc[lt][mt] = (f32x4){0.f, 0.f, 0.f, 0.f};
    }

#pragma unroll
    for (int kk = 0; kk < 2; ++kk) {
#pragma unroll
        for (int lt = 0; lt < 2; ++lt) {
            s16x8 A = *(const s16x8*)&qU[wave * 32 + lt * 16 + fr][kk * 16 + fk * 4];
            zac[lt] = __builtin_amdgcn_mfma_f32_16x16x32_bf16(A, kF[kk], zac[lt], 0, 0, 0);
#pragma unroll
            for (int mt = 0; mt < 4; ++mt)
                acc[lt][mt] = __builtin_amdgcn_mfma_f32_16x16x32_bf16(
                    A, bF[mt][kk], acc[lt][mt], 0, 0, 0);
        }
    }

#pragma unroll
    for (int lt = 0; lt < 2; ++lt) {
#pragma unroll
        for (int reg = 0; reg < 4; ++reg) {
            const int row = blockIdx.x * 128 + wave * 32 + lt * 16 + fk * 4 + reg;
            const float z = 1.0f / (zac[lt][reg] + EPSF);
            float* orow = out + (((size_t)n * LDIM + row) * HDIM + h) * DDIM;
#pragma unroll
            for (int mt = 0; mt < 4; ++mt)
                orow[mt * 16 + fr] = acc[lt][mt][reg] * z;
        }
    }
}

extern "C" void kernel_launch(void* const* d_in, const int* in_sizes, int n_in,
                              void* d_out, int out_size, void* d_ws, size_t ws_size,
                              hipStream_t stream) {
    const float* Q = (const float*)d_in[0];
    const float* K = (const float*)d_in[1];
    const float* V = (const float*)d_in[2];
    float* out = (float*)d_out;

    unsigned short* part = (unsigned short*)d_ws;   // 64*128*4160*2 = 68.2 MB
    unsigned short* kvh  = part + (size_t)NHEADPAIR * CHUNKS * KVSZ;

    dim3 g1(NHEADPAIR, CHUNKS);              // x = nh fastest: page-coherent bursts
    kv_oneshot_kernel<<<g1, 256, 0, stream>>>(K, V, part);
    dim3 gr((KVSZ + 255) / 256, NHEADPAIR);
    kv_reduce_kernel<<<gr, 256, 0, stream>>>(part, kvh);
    dim3 g2(LDIM / 128, NHEADPAIR);
    attn_mfma_kernel<<<g2, 256, 0, stream>>>(Q, kvh, out);
}

// Round 19
// 147.249 us; speedup vs baseline: 1.1966x; 1.0614x over previous
//
#include <hip/hip_runtime.h>
#include <hip/hip_bf16.h>

#define LDIM 8192
#define HDIM 16
#define DDIM 64
#define NHEADPAIR 64          // N*H
#define ROWSTRIDE 1024        // H*D floats between consecutive l for fixed h
#define KVSZ 4160             // 64*64 KV + 64 ksum
#define EPSF 1e-6f
#define CHUNKS 64             // l-chunks per (n,h)
#define RPB 128               // rows per block
#define TROWS 32              // rows per tile
#define NT 4                  // tiles per block
#define DSTR 17               // LDS d-stride in words (odd -> spreads banks)
#define HSTR (64 * DSTR + 5)  // 1093 words per head-array (odd pad -> head spreads banks)

typedef float f32x4 __attribute__((ext_vector_type(4)));
typedef short s16x8 __attribute__((ext_vector_type(8)));   // 8 bf16 (4 VGPRs)

__device__ __forceinline__ float featmap(float x) {
    // elu(x)+1 : x>0 -> x+1 ; x<=0 -> exp(x)
    return x > 0.0f ? x + 1.0f : __expf(x);
}

__device__ __forceinline__ unsigned int pack_bf16x2(float a, float b) {
    union { __hip_bfloat162 h; unsigned int u; } x;
    x.h = __float22bfloat162_rn(make_float2(a, b));   // elem0 -> low 16 bits
    return x.u;
}

__device__ __forceinline__ unsigned short bf16_of(float a) {
    union { __hip_bfloat16 h; unsigned short u; } cv;
    cv.h = __float2bfloat16(a);
    return cv.u;
}

// ---------------- Phase 1 (dense-read MFMA): partial KV[d][m], Ksum[d] --------------
// Block = 8 heads x 128 rows of one n-half: global reads are flat-indexed so every
// wave instruction loads 64 CONSECUTIVE float4 (1KB dense) and every loaded byte is
// consumed (8 heads' 2KB half-rows). This removes the 256B/4KB per-head gather that
// pinned 7 prior kv variants at ~1.8TB/s. Wave = head; LDS per-head transposed
// bf16 tiles with odd-stride padding (~2-way banks); MFMA pattern = validated attn.
__global__ __launch_bounds__(512) void kv_dense_kernel(
    const float* __restrict__ Kp, const float* __restrict__ Vp,
    unsigned short* __restrict__ part)
{
    __shared__ unsigned int KT[8 * HSTR];   // [head][d*DSTR + l-pair slot]
    __shared__ unsigned int VT[8 * HSTR];   // [head][m*DSTR + l-pair slot]

    const int nhf  = blockIdx.x;            // n*2 + half (co-dispatched siblings)
    const int n    = nhf >> 1;
    const int half = nhf & 1;
    const int ch   = blockIdx.y;
    const int t    = threadIdx.x;
    const int wave = t >> 6;                // 0..7 = local head
    const int lane = t & 63;

    // dense staging decomposition: flat float4 index f = t + 512*i
    const int rb    = t >> 7;               // 0..3 (row residue)
    const int pos   = t & 127;
    const int headl = pos >> 4;             // 0..7
    const int dq    = pos & 15;             // 16B granule within the head's 256B

    const float4* K4 = (const float4*)Kp;
    const float4* V4 = (const float4*)Vp;

    const int fr = lane & 15;
    const int fk = lane >> 4;

    f32x4 acc[4][4];                        // [d-band][m-band]
    f32x4 zac[4];
#pragma unroll
    for (int b = 0; b < 4; ++b) {
        zac[b] = (f32x4){0.f, 0.f, 0.f, 0.f};
#pragma unroll
        for (int mb = 0; mb < 4; ++mb) acc[b][mb] = (f32x4){0.f, 0.f, 0.f, 0.f};
    }
    s16x8 ones;
#pragma unroll
    for (int i = 0; i < 8; ++i) ones[i] = (short)0x3F80;   // bf16 1.0

    unsigned int* KTh = &KT[headl * HSTR];
    unsigned int* VTh = &VT[headl * HSTR];
    const unsigned int* KTw = &KT[wave * HSTR];
    const unsigned int* VTw = &VT[wave * HSTR];

    for (int tt = 0; tt < NT; ++tt) {
        const size_t rowbase = (size_t)n * LDIM + (size_t)ch * RPB + tt * TROWS;

        // ---- stage: 4 pair-batches; rows (rb+8pb, rb+8pb+4) -> slot rb+4pb ----
#pragma unroll
        for (int pb = 0; pb < 4; ++pb) {
            const int rlo = rb + 8 * pb;
            const int rhi = rlo + 4;
            const size_t gl = (rowbase + rlo) * 256 + half * 128 + headl * 16 + dq;
            const size_t gh = (rowbase + rhi) * 256 + half * 128 + headl * 16 + dq;
            float4 kl = K4[gl];
            float4 kh = K4[gh];
            float4 vl = V4[gl];
            float4 vh = V4[gh];
            float klf[4] = { featmap(kl.x), featmap(kl.y), featmap(kl.z), featmap(kl.w) };
            float khf[4] = { featmap(kh.x), featmap(kh.y), featmap(kh.z), featmap(kh.w) };
            float vlf[4] = { vl.x, vl.y, vl.z, vl.w };
            float vhf[4] = { vh.x, vh.y, vh.z, vh.w };
            const int s = rb + 4 * pb;
#pragma unroll
            for (int j = 0; j < 4; ++j) {
                const int d = dq * 4 + j;
                KTh[d * DSTR + s] = pack_bf16x2(klf[j], khf[j]);
                VTh[d * DSTR + s] = pack_bf16x2(vlf[j], vhf[j]);
            }
        }
        __syncthreads();

        // ---- compute: wave = head; one K=32 step per tile ----
        union frag { unsigned int u[4]; s16x8 v; };
        frag Bf[4];
#pragma unroll
        for (int mb = 0; mb < 4; ++mb) {
            const int m = 16 * mb + fr;
#pragma unroll
            for (int c = 0; c < 4; ++c) Bf[mb].u[c] = VTw[m * DSTR + fk * 4 + c];
        }
#pragma unroll
        for (int b = 0; b < 4; ++b) {
            frag Af;
            const int d = 16 * b + fr;
#pragma unroll
            for (int c = 0; c < 4; ++c) Af.u[c] = KTw[d * DSTR + fk * 4 + c];
            zac[b] = __builtin_amdgcn_mfma_f32_16x16x32_bf16(Af.v, ones, zac[b], 0, 0, 0);
#pragma unroll
            for (int mb = 0; mb < 4; ++mb)
                acc[b][mb] = __builtin_amdgcn_mfma_f32_16x16x32_bf16(
                    Af.v, Bf[mb].v, acc[b][mb], 0, 0, 0);
        }
        __syncthreads();
    }

    // ---- epilogue: bf16 partial. D row = d (16b+4fk+reg), D col = m (16mb+fr) ----
    const int nh = n * 16 + half * 8 + wave;
    unsigned short* p = part + ((size_t)nh * CHUNKS + ch) * KVSZ;
#pragma unroll
    for (int b = 0; b < 4; ++b)
#pragma unroll
        for (int mb = 0; mb < 4; ++mb)
#pragma unroll
            for (int reg = 0; reg < 4; ++reg)
                p[(16 * b + 4 * fk + reg) * 64 + 16 * mb + fr] = bf16_of(acc[b][mb][reg]);
    if (fr == 0)
#pragma unroll
        for (int b = 0; b < 4; ++b)
#pragma unroll
            for (int reg = 0; reg < 4; ++reg)
                p[4096 + 16 * b + 4 * fk + reg] = bf16_of(zac[b][reg]);
}

// ---------------- Phase 1b: reduce bf16 partials, emit bf16 KV + ksum ---------------
__global__ __launch_bounds__(256) void kv_reduce_kernel(
    const unsigned short* __restrict__ part, unsigned short* __restrict__ kvh)
{
    const int nh = blockIdx.y;
    const int e  = blockIdx.x * 256 + threadIdx.x;
    if (e >= KVSZ) return;
    float s = 0.0f;
    for (int c = 0; c < CHUNKS; ++c) {
        union { unsigned short u; __hip_bfloat16 h; } cv;
        cv.u = part[((size_t)nh * CHUNKS + c) * KVSZ + e];
        s += __bfloat162float(cv.h);
    }
    kvh[(size_t)nh * KVSZ + e] = bf16_of(s);
}

// ---------------- Phase 2 (MFMA): out[l][m] = Z * sum_d fmQ[l][d] * KV[m][d] --------
// Unchanged (validated).
__global__ __launch_bounds__(256) void attn_mfma_kernel(
    const float* __restrict__ Qp, const unsigned short* __restrict__ kvh,
    float* __restrict__ out)
{
    __shared__ unsigned int kvU[64][36];
    __shared__ unsigned int ksU[36];
    __shared__ unsigned int qU[128][36];

    const int nh = blockIdx.y;
    const int n  = nh >> 4;
    const int h  = nh & 15;
    const int t  = threadIdx.x;

    {
        const unsigned int* kvg = (const unsigned int*)(kvh + (size_t)nh * KVSZ);
        const int r  = t >> 2;
        const int c0 = (t & 3) * 8;
        uint4 x = *(const uint4*)(kvg + r * 32 + c0);
        uint4 y = *(const uint4*)(kvg + r * 32 + c0 + 4);
        *(uint4*)&kvU[r][c0]     = x;
        *(uint4*)&kvU[r][c0 + 4] = y;
        if (t < 32) ksU[t] = kvg[2048 + t];
    }

    {
        const int qr = t >> 1;
        const float* qg = Qp + ((((size_t)n * LDIM) + (size_t)blockIdx.x * 128 + qr)
                                * HDIM + h) * DDIM + (t & 1) * 32;
        unsigned int q[16];
#pragma unroll
        for (int j = 0; j < 8; ++j) {
            float4 f = *(const float4*)(qg + j * 4);
            q[2 * j]     = pack_bf16x2(featmap(f.x), featmap(f.y));
            q[2 * j + 1] = pack_bf16x2(featmap(f.z), featmap(f.w));
        }
        uint4* dst = (uint4*)&qU[qr][(t & 1) * 16];
        dst[0] = make_uint4(q[0],  q[1],  q[2],  q[3]);
        dst[1] = make_uint4(q[4],  q[5],  q[6],  q[7]);
        dst[2] = make_uint4(q[8],  q[9],  q[10], q[11]);
        dst[3] = make_uint4(q[12], q[13], q[14], q[15]);
    }
    __syncthreads();

    const int wave = t >> 6;
    const int lane = t & 63;
    const int fr = lane & 15;
    const int fk = lane >> 4;

    s16x8 bF[4][2], kF[2];
#pragma unroll
    for (int mt = 0; mt < 4; ++mt)
#pragma unroll
        for (int kk = 0; kk < 2; ++kk)
            bF[mt][kk] = *(const s16x8*)&kvU[mt * 16 + fr][kk * 16 + fk * 4];
#pragma unroll
    for (int kk = 0; kk < 2; ++kk)
        kF[kk] = *(const s16x8*)&ksU[kk * 16 + fk * 4];

    f32x4 acc[2][4];
    f32x4 zac[2];
#pragma unroll
    for (int lt = 0; lt < 2; ++lt) {
        zac[lt] = (f32x4){0.f, 0.f, 0.f, 0.f};
#pragma unroll
        for (int mt = 0; mt < 4; ++mt) acc[lt][mt] = (f32x4){0.f, 0.f, 0.f, 0.f};
    }

#pragma unroll
    for (int kk = 0; kk < 2; ++kk) {
#pragma unroll
        for (int lt = 0; lt < 2; ++lt) {
            s16x8 A = *(const s16x8*)&qU[wave * 32 + lt * 16 + fr][kk * 16 + fk * 4];
            zac[lt] = __builtin_amdgcn_mfma_f32_16x16x32_bf16(A, kF[kk], zac[lt], 0, 0, 0);
#pragma unroll
            for (int mt = 0; mt < 4; ++mt)
                acc[lt][mt] = __builtin_amdgcn_mfma_f32_16x16x32_bf16(
                    A, bF[mt][kk], acc[lt][mt], 0, 0, 0);
        }
    }

#pragma unroll
    for (int lt = 0; lt < 2; ++lt) {
#pragma unroll
        for (int reg = 0; reg < 4; ++reg) {
            const int row = blockIdx.x * 128 + wave * 32 + lt * 16 + fk * 4 + reg;
            const float z = 1.0f / (zac[lt][reg] + EPSF);
            float* orow = out + (((size_t)n * LDIM + row) * HDIM + h) * DDIM;
#pragma unroll
            for (int mt = 0; mt < 4; ++mt)
                orow[mt * 16 + fr] = acc[lt][mt][reg] * z;
        }
    }
}

extern "C" void kernel_launch(void* const* d_in, const int* in_sizes, int n_in,
                              void* d_out, int out_size, void* d_ws, size_t ws_size,
                              hipStream_t stream) {
    const float* Q = (const float*)d_in[0];
    const float* K = (const float*)d_in[1];
    const float* V = (const float*)d_in[2];
    float* out = (float*)d_out;

    unsigned short* part = (unsigned short*)d_ws;   // 64*64*4160*2 = 34.1 MB
    unsigned short* kvh  = part + (size_t)NHEADPAIR * CHUNKS * KVSZ;

    dim3 g1(8, CHUNKS);                     // x = n*2+half: sibling halves co-dispatch
    kv_dense_kernel<<<g1, 512, 0, stream>>>(K, V, part);
    dim3 gr((KVSZ + 255) / 256, NHEADPAIR);
    kv_reduce_kernel<<<gr, 256, 0, stream>>>(part, kvh);
    dim3 g2(LDIM / 128, NHEADPAIR);
    attn_mfma_kernel<<<g2, 256, 0, stream>>>(Q, kvh, out);
}